// Round 1
// baseline (1139.497 us; speedup 1.0000x reference)
//
#include <hip/hip_runtime.h>
#include <math.h>

// Pipeline:
//   K1: per-thread (pair, l2) fused conv1+pool1+conv2, pool2 via small LDS
//       transpose -> h2p [32768][256]  (k = ci*4 + pos, matches w3 layout)
//   K2: GEMM feat[32768][128] = relu(h2p @ w3^T + b3)
//   K3: logits = feat @ wl^T + bl, softmax -> out [256][3]

__global__ __launch_bounds__(320, 2) void k1_conv(
    const float* __restrict__ x,    // [32768][1216]
    const float* __restrict__ w1,   // [32][10]
    const float* __restrict__ b1,   // [32]
    const float* __restrict__ w2,   // [64][32][3]
    const float* __restrict__ b2,   // [64]
    float* __restrict__ h2p_g)      // [32768][256]
{
    __shared__ float sc[320 * 33];          // padded: lane stride 33 -> conflict-free
    const int tid  = threadIdx.x;
    const int bn0  = blockIdx.x * 32;       // 32 pairs per block
    const int pair = tid / 10;              // 0..31
    const int l2   = tid - pair * 10;       // 0..9 (conv2 output position)
    const float* xr = x + (size_t)(bn0 + pair) * 1216;

    float acc2[64];
    #pragma unroll
    for (int c = 0; c < 64; ++c) acc2[c] = b2[c];   // uniform -> s_load

    // s = conv2 tap index == conv1-pool position offset (stride3, K3, disjoint)
    for (int s = 0; s < 3; ++s) {
        const int l = 3 * l2 + s;           // pooled position, 0..29
        const int base = 40 * l - 4;        // x window [40l-4, 40l+44), 16B aligned
        float xw[48];
        {
            const float4* xp4 = (const float4*)(xr + base);
            #pragma unroll
            for (int i = 0; i < 12; ++i) {
                float4 v;
                if (i == 0) {
                    if (base >= 0) v = xp4[0];
                    else v = make_float4(0.f, 0.f, 0.f, 0.f);  // left zero-pad (l==0)
                } else {
                    v = xp4[i];
                }
                xw[4*i+0] = v.x; xw[4*i+1] = v.y; xw[4*i+2] = v.z; xw[4*i+3] = v.w;
            }
        }

        // conv1 (K=10, stride 8, pad 1) + relu + maxpool5 for this pooled pos
        // x index: 8t + k - 1 = base + 8*dt + 3 + k   (t = 5l + dt)
        float hs[32];
        #pragma unroll
        for (int ci = 0; ci < 32; ++ci) {
            const float* wr = w1 + ci * 10;    // uniform -> s_load
            const float bias = b1[ci];
            float mx = 0.f;                    // relu floor
            #pragma unroll
            for (int dt = 0; dt < 5; ++dt) {
                float a = bias;
                #pragma unroll
                for (int k = 0; k < 10; ++k)
                    a = fmaf(wr[k], xw[8*dt + 3 + k], a);
                mx = fmaxf(mx, a);
            }
            hs[ci] = mx;
        }

        // conv2 partial: tap s into acc2[c]   (weights uniform -> s_load)
        #pragma unroll
        for (int c = 0; c < 64; ++c) {
            float a = acc2[c];
            const float* w2r = w2 + c * 96 + s;
            #pragma unroll
            for (int ci = 0; ci < 32; ++ci)
                a = fmaf(w2r[ci * 3], hs[ci], a);
            acc2[c] = a;
        }
    }

    // pool2 (K=3, stride 3, pad 1) over l2, via LDS, in two 32-channel chunks
    for (int cc = 0; cc < 2; ++cc) {
        #pragma unroll
        for (int c = 0; c < 32; ++c)
            sc[tid * 33 + c] = fmaxf(acc2[cc * 32 + c], 0.f);   // relu(conv2)
        __syncthreads();
        for (int o = tid; o < 4096; o += 320) {   // 32 pairs * 32 ch * 4 pos
            int pr = o >> 7;
            int r  = o & 127;
            int c  = r >> 2;        // chunk-local channel
            int lp = r & 3;         // pooled position
            int q0 = 3 * lp - 1;
            float m = -1e30f;
            #pragma unroll
            for (int d = 0; d < 3; ++d) {
                int q = q0 + d;
                if (q >= 0 && q < 10)
                    m = fmaxf(m, sc[(pr * 10 + q) * 33 + c]);
            }
            h2p_g[(size_t)(bn0 + pr) * 256 + (size_t)(cc * 32 + c) * 4 + lp] =
                fmaxf(m, 0.f);
        }
        __syncthreads();
    }
}

// feat = relu(A @ B^T + b3) : A [32768][256], B = w3 [128][256]
__global__ __launch_bounds__(256, 2) void k2_gemm(
    const float* __restrict__ A,
    const float* __restrict__ B,
    const float* __restrict__ b3,   // [128]
    float* __restrict__ C)          // [32768][128]
{
    __shared__ float sA[128 * 33];
    __shared__ float sB[128 * 33];
    const int tid = threadIdx.x;
    const int m0  = blockIdx.x * 128;
    const int tr  = tid >> 4;       // 0..15
    const int tc  = tid & 15;       // 0..15
    const int rb  = tr * 8;

    float acc[8][8];
    #pragma unroll
    for (int i = 0; i < 8; ++i)
        #pragma unroll
        for (int j = 0; j < 8; ++j) acc[i][j] = 0.f;

    for (int kc = 0; kc < 256; kc += 32) {
        #pragma unroll
        for (int t = 0; t < 16; ++t) {
            int idx = tid + t * 256;        // 0..4095
            int row = idx >> 5, k = idx & 31;
            sA[row * 33 + k] = A[(size_t)(m0 + row) * 256 + kc + k];
            sB[row * 33 + k] = B[(size_t)row * 256 + kc + k];
        }
        __syncthreads();
        #pragma unroll
        for (int k = 0; k < 32; ++k) {
            float av[8], bv[8];
            #pragma unroll
            for (int i = 0; i < 8; ++i) av[i] = sA[(rb + i) * 33 + k];
            #pragma unroll
            for (int j = 0; j < 8; ++j) bv[j] = sB[(tc + 16 * j) * 33 + k];
            #pragma unroll
            for (int i = 0; i < 8; ++i)
                #pragma unroll
                for (int j = 0; j < 8; ++j)
                    acc[i][j] = fmaf(av[i], bv[j], acc[i][j]);
        }
        __syncthreads();
    }
    #pragma unroll
    for (int j = 0; j < 8; ++j) {
        const int col = tc + 16 * j;
        const float bias = b3[col];
        #pragma unroll
        for (int i = 0; i < 8; ++i)
            C[(size_t)(m0 + rb + i) * 128 + col] = fmaxf(acc[i][j] + bias, 0.f);
    }
}

// logits + softmax per batch row
__global__ __launch_bounds__(256, 4) void k3_head(
    const float* __restrict__ feat,   // [256][16384]
    const float* __restrict__ wl,     // [3][16384]
    const float* __restrict__ bl,     // [3]
    float* __restrict__ out)          // [256][3]
{
    __shared__ float red[3][256];
    const int b = blockIdx.x, tid = threadIdx.x;
    const float* f = feat + (size_t)b * 16384;
    float a0 = 0.f, a1 = 0.f, a2 = 0.f;
    for (int k = tid; k < 16384; k += 256) {
        float v = f[k];
        a0 = fmaf(v, wl[k],           a0);
        a1 = fmaf(v, wl[16384 + k],   a1);
        a2 = fmaf(v, wl[32768 + k],   a2);
    }
    red[0][tid] = a0; red[1][tid] = a1; red[2][tid] = a2;
    __syncthreads();
    for (int s = 128; s > 0; s >>= 1) {
        if (tid < s) {
            red[0][tid] += red[0][tid + s];
            red[1][tid] += red[1][tid + s];
            red[2][tid] += red[2][tid + s];
        }
        __syncthreads();
    }
    if (tid == 0) {
        float l0 = red[0][0] + bl[0];
        float l1 = red[1][0] + bl[1];
        float l2 = red[2][0] + bl[2];
        float m  = fmaxf(l0, fmaxf(l1, l2));
        float e0 = expf(l0 - m), e1 = expf(l1 - m), e2 = expf(l2 - m);
        float s  = e0 + e1 + e2;
        out[b * 3 + 0] = e0 / s;
        out[b * 3 + 1] = e1 / s;
        out[b * 3 + 2] = e2 / s;
    }
}

extern "C" void kernel_launch(void* const* d_in, const int* in_sizes, int n_in,
                              void* d_out, int out_size, void* d_ws, size_t ws_size,
                              hipStream_t stream) {
    const float* x  = (const float*)d_in[0];
    const float* w1 = (const float*)d_in[1];
    const float* b1 = (const float*)d_in[2];
    const float* w2 = (const float*)d_in[3];
    const float* b2 = (const float*)d_in[4];
    const float* w3 = (const float*)d_in[5];
    const float* b3 = (const float*)d_in[6];
    const float* wl = (const float*)d_in[7];
    const float* bl = (const float*)d_in[8];
    float* out  = (float*)d_out;
    float* h2p  = (float*)d_ws;                       // 32768*256 floats
    float* feat = h2p + (size_t)32768 * 256;          // 32768*128 floats

    k1_conv<<<1024, 320, 0, stream>>>(x, w1, b1, w2, b2, h2p);
    k2_gemm<<<256, 256, 0, stream>>>(h2p, w3, b3, feat);
    k3_head<<<256, 256, 0, stream>>>(feat, wl, bl, out);
}

// Round 2
// 470.786 us; speedup vs baseline: 2.4204x; 2.4204x over previous
//
#include <hip/hip_runtime.h>
#include <math.h>

// Pipeline:
//   k0: transpose w2 [64][32][3] -> w2t [96][64]  (row k = d*32+ci) so conv2
//       weights become wave-uniform contiguous -> s_load_dwordx16
//   k1: stage A: conv1+pool1 -> LDS h1[16][30][33]; stage B: conv2 with
//       acc[64] in regs + scalar weights; pool2 via LDS reuse -> h2p[32768][256]
//   k2: GEMM feat[32768][128] = relu(h2p @ w3^T + b3)
//   k3: logits = feat @ wl^T + bl, softmax -> out [256][3]

__global__ void k0_w2t(const float* __restrict__ w2, float* __restrict__ w2t) {
    int i = blockIdx.x * 256 + threadIdx.x;     // 6144 elems
    if (i < 6144) {
        int c = i / 96, r = i - c * 96;
        int ci = r / 3, d = r - ci * 3;
        w2t[(d * 32 + ci) * 64 + c] = w2[i];
    }
}

#define NS 16   // series per block

__global__ __launch_bounds__(256, 2) void k1_conv(
    const float* __restrict__ x,    // [32768][1216]
    const float* __restrict__ w1,   // [32][10]
    const float* __restrict__ b1,   // [32]
    const float* __restrict__ w2t,  // [96][64]
    const float* __restrict__ b2,   // [64]
    float* __restrict__ h2p_g)      // [32768][256]
{
    __shared__ float smem[NS * 30 * 33];        // h1, later reused as sh2
    const int tid = threadIdx.x;
    const int bn0 = blockIdx.x * NS;

    // ---- stage A: conv1 (K=10,s=8,p=1) + relu + maxpool5 + relu -> smem
    for (int u = tid; u < NS * 30; u += 256) {
        const int sid = u / 30, p = u - sid * 30;
        const float* xr = x + (size_t)(bn0 + sid) * 1216;
        const int base = 40 * p - 4;            // 16B-aligned window start
        float xw[48];
        {
            const float4* xp4 = (const float4*)(xr + base);
            #pragma unroll
            for (int i = 0; i < 12; ++i) {
                float4 v;
                if (i == 0) {
                    if (base >= 0) v = xp4[0];
                    else v = make_float4(0.f, 0.f, 0.f, 0.f);  // left pad (p==0)
                } else {
                    v = xp4[i];
                }
                xw[4*i+0] = v.x; xw[4*i+1] = v.y; xw[4*i+2] = v.z; xw[4*i+3] = v.w;
            }
        }
        float* dst = smem + u * 33;
        for (int ci = 0; ci < 32; ++ci) {       // dynamic: keep icache small
            const float* wr = w1 + ci * 10;     // uniform -> s_load
            const float bias = b1[ci];
            float mx = 0.f;                     // relu floor (pool window all valid)
            #pragma unroll
            for (int dt = 0; dt < 5; ++dt) {
                float a = bias;
                #pragma unroll
                for (int k = 0; k < 10; ++k)
                    a = fmaf(wr[k], xw[8*dt + 3 + k], a);
                mx = fmaxf(mx, a);
            }
            dst[ci] = mx;
        }
    }
    __syncthreads();

    // ---- stage B: conv2 (K=3,s=3) at position q, all 64 channels in regs
    const int sid = tid / 10, q = tid - sid * 10;
    const bool active = tid < NS * 10;
    float acc[64];
    if (active) {
        #pragma unroll
        for (int c = 0; c < 64; ++c) acc[c] = b2[c];
        const float* srow0 = smem + (sid * 30 + 3 * q) * 33;
        for (int ci = 0; ci < 32; ++ci) {       // dynamic loop: small icache
            float a0 = srow0[ci];
            float a1 = srow0[33 + ci];
            float a2 = srow0[66 + ci];
            const float* wr0 = w2t + ci * 64;            // uniform -> s_load x16
            const float* wr1 = w2t + (32 + ci) * 64;
            const float* wr2 = w2t + (64 + ci) * 64;
            #pragma unroll
            for (int c = 0; c < 64; ++c) {
                float t = fmaf(a0, wr0[c], acc[c]);
                t = fmaf(a1, wr1[c], t);
                acc[c] = fmaf(a2, wr2[c], t);
            }
        }
    }
    __syncthreads();                            // h1 fully consumed

    // ---- relu(conv2) -> sh2[NS][10][65] (reuse smem)
    float* sh2 = smem;
    if (active) {
        #pragma unroll
        for (int c = 0; c < 64; ++c)
            sh2[(sid * 10 + q) * 65 + c] = fmaxf(acc[c], 0.f);
    }
    __syncthreads();

    // ---- pool2 (K=3,s=3,p=1) + relu + coalesced store
    for (int o = tid; o < NS * 256; o += 256) {
        const int s2 = o >> 8;
        const int r  = o & 255;
        const int c  = r >> 2;                  // conv2 channel
        const int lp = r & 3;                   // pooled position
        float m = 0.f;                          // inputs >= 0
        #pragma unroll
        for (int dd = 0; dd < 3; ++dd) {
            int qq = 3 * lp - 1 + dd;
            if (qq >= 0 && qq < 10)
                m = fmaxf(m, sh2[(s2 * 10 + qq) * 65 + c]);
        }
        h2p_g[(size_t)(bn0 + s2) * 256 + r] = m;   // k = c*4 + lp
    }
}

// feat = relu(A @ B^T + b3) : A [32768][256], B = w3 [128][256]
__global__ __launch_bounds__(256, 2) void k2_gemm(
    const float* __restrict__ A,
    const float* __restrict__ B,
    const float* __restrict__ b3,   // [128]
    float* __restrict__ C)          // [32768][128]
{
    __shared__ float sA[128 * 33];
    __shared__ float sB[128 * 33];
    const int tid = threadIdx.x;
    const int m0  = blockIdx.x * 128;
    const int tr  = tid >> 4;       // 0..15
    const int tc  = tid & 15;       // 0..15
    const int rb  = tr * 8;

    float acc[8][8];
    #pragma unroll
    for (int i = 0; i < 8; ++i)
        #pragma unroll
        for (int j = 0; j < 8; ++j) acc[i][j] = 0.f;

    for (int kc = 0; kc < 256; kc += 32) {
        #pragma unroll
        for (int t = 0; t < 16; ++t) {
            int idx = tid + t * 256;        // 0..4095
            int row = idx >> 5, k = idx & 31;
            sA[row * 33 + k] = A[(size_t)(m0 + row) * 256 + kc + k];
            sB[row * 33 + k] = B[(size_t)row * 256 + kc + k];
        }
        __syncthreads();
        #pragma unroll
        for (int k = 0; k < 32; ++k) {
            float av[8], bv[8];
            #pragma unroll
            for (int i = 0; i < 8; ++i) av[i] = sA[(rb + i) * 33 + k];
            #pragma unroll
            for (int j = 0; j < 8; ++j) bv[j] = sB[(tc + 16 * j) * 33 + k];
            #pragma unroll
            for (int i = 0; i < 8; ++i)
                #pragma unroll
                for (int j = 0; j < 8; ++j)
                    acc[i][j] = fmaf(av[i], bv[j], acc[i][j]);
        }
        __syncthreads();
    }
    #pragma unroll
    for (int j = 0; j < 8; ++j) {
        const int col = tc + 16 * j;
        const float bias = b3[col];
        #pragma unroll
        for (int i = 0; i < 8; ++i)
            C[(size_t)(m0 + rb + i) * 128 + col] = fmaxf(acc[i][j] + bias, 0.f);
    }
}

// logits + softmax per batch row
__global__ __launch_bounds__(256, 4) void k3_head(
    const float* __restrict__ feat,   // [256][16384]
    const float* __restrict__ wl,     // [3][16384]
    const float* __restrict__ bl,     // [3]
    float* __restrict__ out)          // [256][3]
{
    __shared__ float red[3][256];
    const int b = blockIdx.x, tid = threadIdx.x;
    const float* f = feat + (size_t)b * 16384;
    float a0 = 0.f, a1 = 0.f, a2 = 0.f;
    for (int k = tid; k < 16384; k += 256) {
        float v = f[k];
        a0 = fmaf(v, wl[k],           a0);
        a1 = fmaf(v, wl[16384 + k],   a1);
        a2 = fmaf(v, wl[32768 + k],   a2);
    }
    red[0][tid] = a0; red[1][tid] = a1; red[2][tid] = a2;
    __syncthreads();
    for (int s = 128; s > 0; s >>= 1) {
        if (tid < s) {
            red[0][tid] += red[0][tid + s];
            red[1][tid] += red[1][tid + s];
            red[2][tid] += red[2][tid + s];
        }
        __syncthreads();
    }
    if (tid == 0) {
        float l0 = red[0][0] + bl[0];
        float l1 = red[1][0] + bl[1];
        float l2 = red[2][0] + bl[2];
        float m  = fmaxf(l0, fmaxf(l1, l2));
        float e0 = expf(l0 - m), e1 = expf(l1 - m), e2 = expf(l2 - m);
        float s  = e0 + e1 + e2;
        out[b * 3 + 0] = e0 / s;
        out[b * 3 + 1] = e1 / s;
        out[b * 3 + 2] = e2 / s;
    }
}

extern "C" void kernel_launch(void* const* d_in, const int* in_sizes, int n_in,
                              void* d_out, int out_size, void* d_ws, size_t ws_size,
                              hipStream_t stream) {
    const float* x  = (const float*)d_in[0];
    const float* w1 = (const float*)d_in[1];
    const float* b1 = (const float*)d_in[2];
    const float* w2 = (const float*)d_in[3];
    const float* b2 = (const float*)d_in[4];
    const float* w3 = (const float*)d_in[5];
    const float* b3 = (const float*)d_in[6];
    const float* wl = (const float*)d_in[7];
    const float* bl = (const float*)d_in[8];
    float* out  = (float*)d_out;
    float* h2p  = (float*)d_ws;                       // 32768*256 floats
    float* feat = h2p + (size_t)32768 * 256;          // 32768*128 floats
    float* w2t  = feat;   // aliases head of feat region; consumed by k1 before
                          // k2 overwrites it (same stream => ordered)

    k0_w2t<<<24, 256, 0, stream>>>(w2, w2t);
    k1_conv<<<32768 / NS, 256, 0, stream>>>(x, w1, b1, w2t, b2, h2p);
    k2_gemm<<<256, 256, 0, stream>>>(h2p, w3, b3, feat);
    k3_head<<<256, 256, 0, stream>>>(feat, wl, bl, out);
}

// Round 3
// 459.887 us; speedup vs baseline: 2.4778x; 1.0237x over previous
//
#include <hip/hip_runtime.h>
#include <math.h>

// Pipeline (bf16 intermediates, fp32 math in convs, MFMA for the big GEMM):
//   k0: w2 [64][32][3] -> w2t [96][64] fp32 (scalar-load friendly);
//       w3 [128][256] fp32 -> w3b bf16
//   k1: NS=32 series/block, 320 thr. Stage A: conv1+pool1 -> LDS h1 bf16
//       [32][30][40]. Stage B: conv2 fp32 acc[64], ALL threads active.
//       pool2 in LDS -> h2p bf16 [32768][256] (k = ci*4 + pos, matches w3)
//   k2: MFMA bf16 GEMM feat[32768][128] = relu(h2p @ w3^T + b3), frags
//       loaded straight from global (A rows 512B, 16B/lane)
//   k3: logits = feat @ wl^T + bl, softmax -> out [256][3]

typedef __attribute__((ext_vector_type(8))) short bf16x8;
typedef __attribute__((ext_vector_type(4))) float f32x4;

__device__ __forceinline__ ushort f2bf(float f) {
    union { float f; uint u; } c; c.f = f;
    return (ushort)((c.u + 0x7FFFu + ((c.u >> 16) & 1u)) >> 16);   // RNE
}
__device__ __forceinline__ float bf2f(ushort h) {
    union { uint u; float f; } c; c.u = ((uint)h) << 16;
    return c.f;
}

__global__ void k0_prep(const float* __restrict__ w2, float* __restrict__ w2t,
                        const float* __restrict__ w3, ushort* __restrict__ w3b) {
    int i = blockIdx.x * 256 + threadIdx.x;
    if (i < 6144) {                         // w2 transpose: [c][ci][d] -> [d*32+ci][c]
        int c = i / 96, r = i - c * 96;
        int ci = r / 3, d = r - ci * 3;
        w2t[(d * 32 + ci) * 64 + c] = w2[i];
    }
    int j = i - 6144;
    if (j >= 0 && j < 32768) w3b[j] = f2bf(w3[j]);
}

#define NS 32   // series per block

__global__ __launch_bounds__(320, 2) void k1_conv(
    const float* __restrict__ x,    // [32768][1216]
    const float* __restrict__ w1,   // [32][10]
    const float* __restrict__ b1,   // [32]
    const float* __restrict__ w2t,  // [96][64]
    const float* __restrict__ b2,   // [64]
    ushort* __restrict__ h2p_g)     // [32768][256] bf16
{
    __shared__ ushort smem[NS * 30 * 40];   // h1 bf16, 76.8 KB; later reused as sh2
    const int tid = threadIdx.x;
    const int bn0 = blockIdx.x * NS;

    // ---- stage A: conv1 (K=10,s=8,p=1) + relu + maxpool5 -> h1 (bf16)
    for (int u = tid; u < NS * 30; u += 320) {
        const int sid = u / 30, p = u - sid * 30;
        const float* xr = x + (size_t)(bn0 + sid) * 1216;
        const int base = 40 * p - 4;        // 16B-aligned window start
        float xw[48];
        {
            const float4* xp4 = (const float4*)(xr + base);
            #pragma unroll
            for (int i = 0; i < 12; ++i) {
                float4 v;
                if (i == 0) {
                    if (base >= 0) v = xp4[0];
                    else v = make_float4(0.f, 0.f, 0.f, 0.f);  // left pad (p==0)
                } else {
                    v = xp4[i];
                }
                xw[4*i+0] = v.x; xw[4*i+1] = v.y; xw[4*i+2] = v.z; xw[4*i+3] = v.w;
            }
        }
        uint* drow = (uint*)(smem + u * 40);            // 80B row, 4B-aligned
        for (int ci = 0; ci < 32; ci += 2) {            // dynamic: small icache
            uint pp = 0;
            #pragma unroll
            for (int h = 0; h < 2; ++h) {
                const float* wr = w1 + (ci + h) * 10;   // uniform -> s_load
                const float bias = b1[ci + h];
                float mx = 0.f;                         // relu floor
                #pragma unroll
                for (int dt = 0; dt < 5; ++dt) {
                    float a = bias;
                    #pragma unroll
                    for (int k = 0; k < 10; ++k)
                        a = fmaf(wr[k], xw[8*dt + 3 + k], a);
                    mx = fmaxf(mx, a);
                }
                pp |= ((uint)f2bf(mx)) << (16 * h);
            }
            drow[ci >> 1] = pp;
        }
    }
    __syncthreads();

    // ---- stage B: conv2 (K=3,s=3) — all 320 threads active, acc in regs
    const int sid = tid / 10, q = tid - sid * 10;
    float acc[64];
    #pragma unroll
    for (int c = 0; c < 64; ++c) acc[c] = b2[c];
    {
        const ushort* srow = smem + (sid * 30 + 3 * q) * 40;
        for (int ci = 0; ci < 32; ++ci) {               // dynamic: small icache
            float a0 = bf2f(srow[ci]);
            float a1 = bf2f(srow[40 + ci]);
            float a2 = bf2f(srow[80 + ci]);
            const float* wr0 = w2t + ci * 64;           // uniform -> s_load
            const float* wr1 = w2t + (32 + ci) * 64;
            const float* wr2 = w2t + (64 + ci) * 64;
            #pragma unroll
            for (int c = 0; c < 64; ++c) {
                float t = fmaf(a0, wr0[c], acc[c]);
                t = fmaf(a1, wr1[c], t);
                acc[c] = fmaf(a2, wr2[c], t);
            }
        }
    }
    __syncthreads();                                    // h1 fully consumed

    // ---- relu(conv2) -> sh2 bf16 [320 rows][72]  (reuse smem, 46 KB)
    {
        uint4* dst = (uint4*)(smem + (sid * 10 + q) * 72);   // 144B rows, 16B-aligned
        #pragma unroll
        for (int i = 0; i < 8; ++i) {
            uint p0 = (uint)f2bf(fmaxf(acc[8*i+0], 0.f)) | ((uint)f2bf(fmaxf(acc[8*i+1], 0.f)) << 16);
            uint p1 = (uint)f2bf(fmaxf(acc[8*i+2], 0.f)) | ((uint)f2bf(fmaxf(acc[8*i+3], 0.f)) << 16);
            uint p2 = (uint)f2bf(fmaxf(acc[8*i+4], 0.f)) | ((uint)f2bf(fmaxf(acc[8*i+5], 0.f)) << 16);
            uint p3 = (uint)f2bf(fmaxf(acc[8*i+6], 0.f)) | ((uint)f2bf(fmaxf(acc[8*i+7], 0.f)) << 16);
            dst[i] = make_uint4(p0, p1, p2, p3);
        }
    }
    __syncthreads();

    // ---- pool2 (K=3,s=3,p=1) + store bf16 (values >= 0: ushort max == fp max)
    for (int o = tid; o < NS * 256; o += 320) {
        const int s2 = o >> 8;
        const int r  = o & 255;
        const int c  = r >> 2;                  // conv2 channel
        const int lp = r & 3;                   // pooled position
        ushort m = 0;
        #pragma unroll
        for (int dd = 0; dd < 3; ++dd) {
            int qq = 3 * lp - 1 + dd;
            if (qq >= 0 && qq < 10) {
                ushort v = smem[(s2 * 10 + qq) * 72 + c];
                m = (v > m) ? v : m;
            }
        }
        h2p_g[(size_t)(bn0 + s2) * 256 + r] = m;   // k = c*4 + lp
    }
}

// feat = relu(A @ B^T + b3) via bf16 MFMA; A [32768][256], B = w3b [128][256]
__global__ __launch_bounds__(256, 2) void k2_gemm(
    const ushort* __restrict__ A,
    const ushort* __restrict__ B,
    const float* __restrict__ b3,   // [128] fp32
    float* __restrict__ C)          // [32768][128] fp32
{
    const int tid  = threadIdx.x;
    const int wv   = tid >> 6;          // wave 0..3 -> 16-row M strip
    const int lane = tid & 63;
    const int lm   = lane & 15;         // m (A) / n (B) / col (D)
    const int quad = lane >> 4;         // k-offset/8 (A,B), row-offset/4 (D)
    const int m0   = blockIdx.x * 64 + wv * 16;

    f32x4 acc[8];
    #pragma unroll
    for (int t = 0; t < 8; ++t) acc[t] = (f32x4){0.f, 0.f, 0.f, 0.f};

    const ushort* arow = A + (size_t)(m0 + lm) * 256 + quad * 8;
    const ushort* brow = B + (size_t)lm * 256 + quad * 8;
    #pragma unroll
    for (int kc = 0; kc < 256; kc += 32) {
        bf16x8 af = *(const bf16x8*)(arow + kc);
        #pragma unroll
        for (int nt = 0; nt < 8; ++nt) {
            bf16x8 bfr = *(const bf16x8*)(brow + nt * 4096 + kc);   // 16 rows * 256
            acc[nt] = __builtin_amdgcn_mfma_f32_16x16x32_bf16(af, bfr, acc[nt], 0, 0, 0);
        }
    }
    #pragma unroll
    for (int nt = 0; nt < 8; ++nt) {
        const int col = nt * 16 + lm;
        const float bias = b3[col];
        #pragma unroll
        for (int r = 0; r < 4; ++r) {
            const int row = m0 + quad * 4 + r;          // verified C/D layout
            C[(size_t)row * 128 + col] = fmaxf(acc[nt][r] + bias, 0.f);
        }
    }
}

// logits + softmax per batch row
__global__ __launch_bounds__(256, 4) void k3_head(
    const float* __restrict__ feat,   // [256][16384]
    const float* __restrict__ wl,     // [3][16384]
    const float* __restrict__ bl,     // [3]
    float* __restrict__ out)          // [256][3]
{
    __shared__ float red[3][256];
    const int b = blockIdx.x, tid = threadIdx.x;
    const float4* f4 = (const float4*)(feat + (size_t)b * 16384);
    const float4* u0 = (const float4*)(wl);
    const float4* u1 = (const float4*)(wl + 16384);
    const float4* u2 = (const float4*)(wl + 32768);
    float a0 = 0.f, a1 = 0.f, a2 = 0.f;
    for (int k = tid; k < 4096; k += 256) {
        float4 v  = f4[k];
        float4 w0 = u0[k], w1 = u1[k], w2 = u2[k];
        a0 = fmaf(v.x, w0.x, fmaf(v.y, w0.y, fmaf(v.z, w0.z, fmaf(v.w, w0.w, a0))));
        a1 = fmaf(v.x, w1.x, fmaf(v.y, w1.y, fmaf(v.z, w1.z, fmaf(v.w, w1.w, a1))));
        a2 = fmaf(v.x, w2.x, fmaf(v.y, w2.y, fmaf(v.z, w2.z, fmaf(v.w, w2.w, a2))));
    }
    red[0][tid] = a0; red[1][tid] = a1; red[2][tid] = a2;
    __syncthreads();
    for (int s = 128; s > 0; s >>= 1) {
        if (tid < s) {
            red[0][tid] += red[0][tid + s];
            red[1][tid] += red[1][tid + s];
            red[2][tid] += red[2][tid + s];
        }
        __syncthreads();
    }
    if (tid == 0) {
        float l0 = red[0][0] + bl[0];
        float l1 = red[1][0] + bl[1];
        float l2 = red[2][0] + bl[2];
        float m  = fmaxf(l0, fmaxf(l1, l2));
        float e0 = expf(l0 - m), e1 = expf(l1 - m), e2 = expf(l2 - m);
        float s  = e0 + e1 + e2;
        out[b * 3 + 0] = e0 / s;
        out[b * 3 + 1] = e1 / s;
        out[b * 3 + 2] = e2 / s;
    }
}

extern "C" void kernel_launch(void* const* d_in, const int* in_sizes, int n_in,
                              void* d_out, int out_size, void* d_ws, size_t ws_size,
                              hipStream_t stream) {
    const float* x  = (const float*)d_in[0];
    const float* w1 = (const float*)d_in[1];
    const float* b1 = (const float*)d_in[2];
    const float* w2 = (const float*)d_in[3];
    const float* b2 = (const float*)d_in[4];
    const float* w3 = (const float*)d_in[5];
    const float* b3 = (const float*)d_in[6];
    const float* wl = (const float*)d_in[7];
    const float* bl = (const float*)d_in[8];
    float* out = (float*)d_out;

    // workspace layout (re-written every launch; harness poisons ws with 0xAA)
    ushort* h2p  = (ushort*)d_ws;                                  // 16 MB
    float*  feat = (float*)((char*)d_ws + (size_t)32768 * 256 * 2); // 16 MB
    float*  w2t  = (float*)((char*)feat + (size_t)32768 * 128 * 4); // 24 KB
    ushort* w3b  = (ushort*)((char*)w2t + 96 * 64 * 4);             // 64 KB

    k0_prep<<<152, 256, 0, stream>>>(w2, w2t, w3, w3b);
    k1_conv<<<32768 / NS, 320, 0, stream>>>(x, w1, b1, w2t, b2, h2p);
    k2_gemm<<<512, 256, 0, stream>>>(h2p, w3b, b3, feat);
    k3_head<<<256, 256, 0, stream>>>(feat, wl, bl, out);
}

// Round 4
// 362.649 us; speedup vs baseline: 3.1421x; 1.2681x over previous
//
#include <hip/hip_runtime.h>
#include <math.h>

// Pipeline (all conv stages LDS-free):
//   k0 : w2 [64][32][3] -> w2b bf16 [64][96] (k = s*32+ci); w3 -> w3b bf16
//   k1a: conv1(K=10,s=8,p=1)+relu+maxpool5 -> h1g bf16, q-major rows:
//        h1g[(q*BNC+bn)*96 + s*32 + ci]  == im2col of conv2 (stride==K!)
//   k1b: conv2 as MFMA GEMM [BNC*10 x 96] @ w2b^T, bias+relu+pool2+relu
//        collapsed per-lane in registers -> h2p bf16 [32768][256] (k=ci*4+lp)
//   k2 : MFMA GEMM feat[32768][128] = relu(h2p @ w3b^T + b3)
//   k3 : logits = feat @ wl^T + bl, softmax -> out [256][3]
//   h1g chunked x2 (31.5MB reused; feat aliases it) -> ws 46.1MB < proven 48MB

typedef __attribute__((ext_vector_type(8))) short bf16x8;
typedef __attribute__((ext_vector_type(4))) float f32x4;

__device__ __forceinline__ ushort f2bf(float f) {
    union { float f; uint u; } c; c.f = f;
    return (ushort)((c.u + 0x7FFFu + ((c.u >> 16) & 1u)) >> 16);   // RNE
}

#define BNC 16384   // series per chunk (2 chunks of 32768)

__global__ void k0_prep(const float* __restrict__ w2, ushort* __restrict__ w2b,
                        const float* __restrict__ w3, ushort* __restrict__ w3b) {
    int i = blockIdx.x * 256 + threadIdx.x;
    if (i < 6144) {                     // w2[c][ci][d] -> w2b[c][d*32+ci]
        int c = i / 96, r = i - c * 96;
        int ci = r / 3, d = r - ci * 3;
        w2b[c * 96 + d * 32 + ci] = f2bf(w2[i]);
    }
    int j = i - 6144;
    if (j >= 0 && j < 32768) w3b[j] = f2bf(w3[j]);
}

// conv1 + pool1, streaming, no LDS. thread = (q, bn); writes 192B contiguous.
__global__ __launch_bounds__(256) void k1a_conv1(
    const float* __restrict__ x,    // chunk base [BNC][1216]
    const float* __restrict__ w1,   // [32][10]
    const float* __restrict__ b1,   // [32]
    ushort* __restrict__ h1g)       // [10][BNC][96]
{
    const int t  = blockIdx.x * 256 + threadIdx.x;
    const int q  = t >> 14;                 // BNC = 2^14: q wave-uniform
    const int bn = t & (BNC - 1);
    const float* xr = x + (size_t)bn * 1216;
    uint4* drow = (uint4*)(h1g + ((size_t)q * BNC + bn) * 96);

    for (int s = 0; s < 3; ++s) {
        const int p = 3 * q + s;            // pooled position 0..29
        const int base = 40 * p - 4;        // 16B-aligned window start
        float xw[48];
        const float4* xp4 = (const float4*)(xr + base);
        #pragma unroll
        for (int i = 0; i < 12; ++i) {
            float4 v;
            if (i == 0) {
                if (base >= 0) v = xp4[0];          // wave-uniform branch
                else v = make_float4(0.f, 0.f, 0.f, 0.f);   // left pad (p==0)
            } else {
                v = xp4[i];
            }
            xw[4*i] = v.x; xw[4*i+1] = v.y; xw[4*i+2] = v.z; xw[4*i+3] = v.w;
        }
        for (int cg = 0; cg < 4; ++cg) {    // dynamic: small icache
            uint pk[4];
            #pragma unroll
            for (int h2 = 0; h2 < 4; ++h2) {
                uint pp = 0;
                #pragma unroll
                for (int hh = 0; hh < 2; ++hh) {
                    const int ci = cg * 8 + h2 * 2 + hh;
                    const float* wr = w1 + ci * 10;     // uniform -> s_load
                    const float bias = b1[ci];
                    float mx = 0.f;                     // relu floor
                    #pragma unroll
                    for (int dt = 0; dt < 5; ++dt) {
                        float a = bias;
                        #pragma unroll
                        for (int k = 0; k < 10; ++k)
                            a = fmaf(wr[k], xw[8*dt + 3 + k], a);
                        mx = fmaxf(mx, a);
                    }
                    pp |= ((uint)f2bf(mx)) << (16 * hh);
                }
                pk[h2] = pp;
            }
            drow[s * 4 + cg] = make_uint4(pk[0], pk[1], pk[2], pk[3]);
        }
    }
}

// conv2 via MFMA + bias + relu + pool2(+relu) per-lane, no LDS.
// block = 4 waves; wave w = output cols [w*16, w*16+16); block rows = 16 series.
__global__ __launch_bounds__(256) void k1b_conv2(
    const ushort* __restrict__ h1g,  // [10][BNC][96]
    const ushort* __restrict__ w2b,  // [64][96]
    const float* __restrict__ b2,    // [64]
    ushort* __restrict__ h2p,        // [32768][256]
    int bn_base)
{
    const int w    = threadIdx.x >> 6;
    const int lane = threadIdx.x & 63;
    const int lm   = lane & 15;
    const int quad = lane >> 4;
    const int bn0  = blockIdx.x * 16;
    const int col  = w * 16 + lm;           // conv2 channel

    bf16x8 bfrag[3];
    #pragma unroll
    for (int kc = 0; kc < 3; ++kc)          // B[n=col][k=kc*32+quad*8 ..]
        bfrag[kc] = *(const bf16x8*)(w2b + col * 96 + kc * 32 + quad * 8);

    f32x4 acc[10];
    #pragma unroll
    for (int q = 0; q < 10; ++q) acc[q] = (f32x4){0.f, 0.f, 0.f, 0.f};

    const ushort* abase = h1g + ((size_t)(bn0 + lm)) * 96 + quad * 8;
    #pragma unroll
    for (int q = 0; q < 10; ++q) {
        const ushort* ar = abase + (size_t)q * (BNC * 96);
        #pragma unroll
        for (int kc = 0; kc < 3; ++kc) {
            bf16x8 af = *(const bf16x8*)(ar + kc * 32);
            acc[q] = __builtin_amdgcn_mfma_f32_16x16x32_bf16(af, bfrag[kc], acc[q], 0, 0, 0);
        }
    }

    // D layout: col = lane&15, row = quad*4 + reg (verified). Pool over q
    // windows {0,1},{2,3,4},{5,6,7},{8,9} entirely in registers.
    const float bias = b2[col];
    #pragma unroll
    for (int r = 0; r < 4; ++r) {
        const int bn = bn0 + quad * 4 + r;
        float v[10];
        #pragma unroll
        for (int q = 0; q < 10; ++q) v[q] = acc[q][r] + bias;
        float lp0 = fmaxf(0.f, fmaxf(v[0], v[1]));
        float lp1 = fmaxf(fmaxf(v[2], v[3]), fmaxf(v[4], 0.f));
        float lp2 = fmaxf(fmaxf(v[5], v[6]), fmaxf(v[7], 0.f));
        float lp3 = fmaxf(0.f, fmaxf(v[8], v[9]));
        uint lo = (uint)f2bf(lp0) | ((uint)f2bf(lp1) << 16);
        uint hi = (uint)f2bf(lp2) | ((uint)f2bf(lp3) << 16);
        *(uint2*)(h2p + (size_t)(bn_base + bn) * 256 + col * 4) = make_uint2(lo, hi);
    }
}

// feat = relu(A @ B^T + b3) via bf16 MFMA; A [32768][256], B = w3b [128][256]
__global__ __launch_bounds__(256, 2) void k2_gemm(
    const ushort* __restrict__ A,
    const ushort* __restrict__ B,
    const float* __restrict__ b3,   // [128] fp32
    float* __restrict__ C)          // [32768][128] fp32
{
    const int tid  = threadIdx.x;
    const int wv   = tid >> 6;
    const int lane = tid & 63;
    const int lm   = lane & 15;
    const int quad = lane >> 4;
    const int m0   = blockIdx.x * 64 + wv * 16;

    f32x4 acc[8];
    #pragma unroll
    for (int t = 0; t < 8; ++t) acc[t] = (f32x4){0.f, 0.f, 0.f, 0.f};

    const ushort* arow = A + (size_t)(m0 + lm) * 256 + quad * 8;
    const ushort* brow = B + (size_t)lm * 256 + quad * 8;
    #pragma unroll
    for (int kc = 0; kc < 256; kc += 32) {
        bf16x8 af = *(const bf16x8*)(arow + kc);
        #pragma unroll
        for (int nt = 0; nt < 8; ++nt) {
            bf16x8 bfr = *(const bf16x8*)(brow + nt * 4096 + kc);
            acc[nt] = __builtin_amdgcn_mfma_f32_16x16x32_bf16(af, bfr, acc[nt], 0, 0, 0);
        }
    }
    #pragma unroll
    for (int nt = 0; nt < 8; ++nt) {
        const int col = nt * 16 + lm;
        const float bias = b3[col];
        #pragma unroll
        for (int r = 0; r < 4; ++r) {
            const int row = m0 + quad * 4 + r;
            C[(size_t)row * 128 + col] = fmaxf(acc[nt][r] + bias, 0.f);
        }
    }
}

// logits + softmax per batch row
__global__ __launch_bounds__(256, 4) void k3_head(
    const float* __restrict__ feat,   // [256][16384]
    const float* __restrict__ wl,     // [3][16384]
    const float* __restrict__ bl,     // [3]
    float* __restrict__ out)          // [256][3]
{
    __shared__ float red[3][256];
    const int b = blockIdx.x, tid = threadIdx.x;
    const float4* f4 = (const float4*)(feat + (size_t)b * 16384);
    const float4* u0 = (const float4*)(wl);
    const float4* u1 = (const float4*)(wl + 16384);
    const float4* u2 = (const float4*)(wl + 32768);
    float a0 = 0.f, a1 = 0.f, a2 = 0.f;
    for (int k = tid; k < 4096; k += 256) {
        float4 v  = f4[k];
        float4 w0 = u0[k], w1 = u1[k], w2 = u2[k];
        a0 = fmaf(v.x, w0.x, fmaf(v.y, w0.y, fmaf(v.z, w0.z, fmaf(v.w, w0.w, a0))));
        a1 = fmaf(v.x, w1.x, fmaf(v.y, w1.y, fmaf(v.z, w1.z, fmaf(v.w, w1.w, a1))));
        a2 = fmaf(v.x, w2.x, fmaf(v.y, w2.y, fmaf(v.z, w2.z, fmaf(v.w, w2.w, a2))));
    }
    red[0][tid] = a0; red[1][tid] = a1; red[2][tid] = a2;
    __syncthreads();
    for (int s = 128; s > 0; s >>= 1) {
        if (tid < s) {
            red[0][tid] += red[0][tid + s];
            red[1][tid] += red[1][tid + s];
            red[2][tid] += red[2][tid + s];
        }
        __syncthreads();
    }
    if (tid == 0) {
        float l0 = red[0][0] + bl[0];
        float l1 = red[1][0] + bl[1];
        float l2 = red[2][0] + bl[2];
        float m  = fmaxf(l0, fmaxf(l1, l2));
        float e0 = expf(l0 - m), e1 = expf(l1 - m), e2 = expf(l2 - m);
        float s  = e0 + e1 + e2;
        out[b * 3 + 0] = e0 / s;
        out[b * 3 + 1] = e1 / s;
        out[b * 3 + 2] = e2 / s;
    }
}

extern "C" void kernel_launch(void* const* d_in, const int* in_sizes, int n_in,
                              void* d_out, int out_size, void* d_ws, size_t ws_size,
                              hipStream_t stream) {
    const float* x  = (const float*)d_in[0];
    const float* w1 = (const float*)d_in[1];
    const float* b1 = (const float*)d_in[2];
    const float* w2 = (const float*)d_in[3];
    const float* b2 = (const float*)d_in[4];
    const float* w3 = (const float*)d_in[5];
    const float* b3 = (const float*)d_in[6];
    const float* wl = (const float*)d_in[7];
    const float* bl = (const float*)d_in[8];
    float* out = (float*)d_out;

    // ws layout (46.1 MB total, < 48 MB proven in round 1):
    //   [0, 31457280)          h1g chunk (10*BNC*96 bf16); feat aliases after
    //   [31457280, 48234496)   h2p  32768*256 bf16
    //   [48234496, 48246784)   w2b  64*96 bf16
    //   [48246784, 48312320)   w3b  128*256 bf16
    ushort* h1g  = (ushort*)d_ws;
    float*  feat = (float*)d_ws;            // 16MB, alias: h1g dead before k2
    ushort* h2p  = (ushort*)((char*)d_ws + 31457280);
    ushort* w2b  = (ushort*)((char*)d_ws + 48234496);
    ushort* w3b  = (ushort*)((char*)d_ws + 48246784);

    k0_prep<<<156, 256, 0, stream>>>(w2, w2b, w3, w3b);
    for (int c = 0; c < 2; ++c) {
        k1a_conv1<<<BNC * 10 / 256, 256, 0, stream>>>(
            x + (size_t)c * BNC * 1216, w1, b1, h1g);
        k1b_conv2<<<BNC / 16, 256, 0, stream>>>(h1g, w2b, b2, h2p, c * BNC);
    }
    k2_gemm<<<512, 256, 0, stream>>>(h2p, w3b, b3, feat);
    k3_head<<<256, 256, 0, stream>>>(feat, wl, bl, out);
}

// Round 5
// 328.321 us; speedup vs baseline: 3.4707x; 1.1046x over previous
//
#include <hip/hip_runtime.h>
#include <math.h>

// Pipeline (single pass, all conv stages LDS-free):
//   k0 : w2 [64][32][3] -> w2b bf16 [64][96] (k = s*32+ci); w3 -> w3b bf16
//   k1a: conv1(K=10,s=8,p=1)+relu+maxpool5 -> h1g bf16 [10][32768][96],
//        thread = (p, bn), one pooled position each (short dep chains);
//        h1g row layout == im2col of conv2 (stride==K => pure reshape)
//   k1b: conv2 as MFMA GEMM + bias+relu+pool2(+relu) per-lane in registers
//        -> h2p bf16 [32768][256] (k = ci*4 + lp, matches w3 layout)
//   k2 : MFMA GEMM feat[32768][128] = relu(h2p @ w3b^T + b3)
//   k3 : logits = feat @ wl^T + bl, softmax -> out [256][3]
// ws: fill counters show d_ws >= 600MB; we use ~80MB, feat aliases dead h1g.

typedef __attribute__((ext_vector_type(8))) short bf16x8;
typedef __attribute__((ext_vector_type(4))) float f32x4;

__device__ __forceinline__ ushort f2bf(float f) {
    union { float f; uint u; } c; c.f = f;
    return (ushort)((c.u + 0x7FFFu + ((c.u >> 16) & 1u)) >> 16);   // RNE
}

#define BN 32768

__global__ void k0_prep(const float* __restrict__ w2, ushort* __restrict__ w2b,
                        const float* __restrict__ w3, ushort* __restrict__ w3b) {
    int i = blockIdx.x * 256 + threadIdx.x;
    if (i < 6144) {                     // w2[c][ci][d] -> w2b[c][d*32+ci]
        int c = i / 96, r = i - c * 96;
        int ci = r / 3, d = r - ci * 3;
        w2b[c * 96 + d * 32 + ci] = f2bf(w2[i]);
    }
    int j = i - 6144;
    if (j >= 0 && j < 32768) w3b[j] = f2bf(w3[j]);
}

// conv1 + pool1, streaming, no LDS. thread = (p, bn): ONE pooled position.
__global__ __launch_bounds__(256) void k1a_conv1(
    const float* __restrict__ x,    // [32768][1216]
    const float* __restrict__ w1,   // [32][10]
    const float* __restrict__ b1,   // [32]
    ushort* __restrict__ h1g)       // [10][32768][96]
{
    const int t  = blockIdx.x * 256 + threadIdx.x;
    const int p  = t >> 15;                 // 0..29, wave-uniform (BN = 2^15)
    const int bn = t & (BN - 1);
    const int q  = p / 3;                   // conv2 position (uniform)
    const int s  = p - 3 * q;               // conv2 tap     (uniform)
    const float* xr = x + (size_t)bn * 1216;
    const int base = 40 * p - 4;            // 16B-aligned window start

    float xw[48];
    {
        const float4* xp4 = (const float4*)(xr + base);
        #pragma unroll
        for (int i = 0; i < 12; ++i) {
            float4 v;
            if (i == 0) {
                if (base >= 0) v = xp4[0];  // wave-uniform branch
                else v = make_float4(0.f, 0.f, 0.f, 0.f);   // left pad (p==0)
            } else {
                v = xp4[i];
            }
            xw[4*i] = v.x; xw[4*i+1] = v.y; xw[4*i+2] = v.z; xw[4*i+3] = v.w;
        }
    }

    uint4* drow = (uint4*)(h1g + ((size_t)q * BN + bn) * 96 + s * 32);
    for (int cg = 0; cg < 4; ++cg) {        // dynamic: small icache
        uint pk[4];
        #pragma unroll
        for (int h2 = 0; h2 < 4; ++h2) {
            uint pp = 0;
            #pragma unroll
            for (int hh = 0; hh < 2; ++hh) {
                const int ci = cg * 8 + h2 * 2 + hh;
                const float* wr = w1 + ci * 10;     // uniform -> s_load
                const float bias = b1[ci];
                float mx = 0.f;                     // relu floor
                #pragma unroll
                for (int dt = 0; dt < 5; ++dt) {
                    float a = bias;
                    #pragma unroll
                    for (int k = 0; k < 10; ++k)
                        a = fmaf(wr[k], xw[8*dt + 3 + k], a);
                    mx = fmaxf(mx, a);
                }
                pp |= ((uint)f2bf(mx)) << (16 * hh);
            }
            pk[h2] = pp;
        }
        drow[cg] = make_uint4(pk[0], pk[1], pk[2], pk[3]);
    }
}

// conv2 via MFMA + bias + relu + pool2(+relu) per-lane, no LDS.
// block = 4 waves; wave w = cols [w*16, w*16+16); block rows = 16 series.
__global__ __launch_bounds__(256) void k1b_conv2(
    const ushort* __restrict__ h1g,  // [10][BN][96]
    const ushort* __restrict__ w2b,  // [64][96]
    const float* __restrict__ b2,    // [64]
    ushort* __restrict__ h2p)        // [32768][256]
{
    const int w    = threadIdx.x >> 6;
    const int lane = threadIdx.x & 63;
    const int lm   = lane & 15;
    const int quad = lane >> 4;
    const int bn0  = blockIdx.x * 16;
    const int col  = w * 16 + lm;           // conv2 channel

    bf16x8 bfrag[3];
    #pragma unroll
    for (int kc = 0; kc < 3; ++kc)          // B[n=col][k=kc*32+quad*8 ..]
        bfrag[kc] = *(const bf16x8*)(w2b + col * 96 + kc * 32 + quad * 8);

    f32x4 acc[10];
    #pragma unroll
    for (int q = 0; q < 10; ++q) acc[q] = (f32x4){0.f, 0.f, 0.f, 0.f};

    const ushort* abase = h1g + ((size_t)(bn0 + lm)) * 96 + quad * 8;
    #pragma unroll
    for (int q = 0; q < 10; ++q) {
        const ushort* ar = abase + (size_t)q * (BN * 96);
        #pragma unroll
        for (int kc = 0; kc < 3; ++kc) {
            bf16x8 af = *(const bf16x8*)(ar + kc * 32);
            acc[q] = __builtin_amdgcn_mfma_f32_16x16x32_bf16(af, bfrag[kc], acc[q], 0, 0, 0);
        }
    }

    // D layout: col = lane&15, row = quad*4 + reg (verified). Pool over q
    // windows {0,1},{2,3,4},{5,6,7},{8,9} entirely in registers.
    const float bias = b2[col];
    #pragma unroll
    for (int r = 0; r < 4; ++r) {
        const int bn = bn0 + quad * 4 + r;
        float v[10];
        #pragma unroll
        for (int q = 0; q < 10; ++q) v[q] = acc[q][r] + bias;
        float lp0 = fmaxf(0.f, fmaxf(v[0], v[1]));
        float lp1 = fmaxf(fmaxf(v[2], v[3]), fmaxf(v[4], 0.f));
        float lp2 = fmaxf(fmaxf(v[5], v[6]), fmaxf(v[7], 0.f));
        float lp3 = fmaxf(0.f, fmaxf(v[8], v[9]));
        uint lo = (uint)f2bf(lp0) | ((uint)f2bf(lp1) << 16);
        uint hi = (uint)f2bf(lp2) | ((uint)f2bf(lp3) << 16);
        *(uint2*)(h2p + (size_t)bn * 256 + col * 4) = make_uint2(lo, hi);
    }
}

// feat = relu(A @ B^T + b3) via bf16 MFMA; A [32768][256], B = w3b [128][256]
__global__ __launch_bounds__(256, 2) void k2_gemm(
    const ushort* __restrict__ A,
    const ushort* __restrict__ B,
    const float* __restrict__ b3,   // [128] fp32
    float* __restrict__ C)          // [32768][128] fp32
{
    const int tid  = threadIdx.x;
    const int wv   = tid >> 6;
    const int lane = tid & 63;
    const int lm   = lane & 15;
    const int quad = lane >> 4;
    const int m0   = blockIdx.x * 64 + wv * 16;

    f32x4 acc[8];
    #pragma unroll
    for (int t = 0; t < 8; ++t) acc[t] = (f32x4){0.f, 0.f, 0.f, 0.f};

    const ushort* arow = A + (size_t)(m0 + lm) * 256 + quad * 8;
    const ushort* brow = B + (size_t)lm * 256 + quad * 8;
    #pragma unroll
    for (int kc = 0; kc < 256; kc += 32) {
        bf16x8 af = *(const bf16x8*)(arow + kc);
        #pragma unroll
        for (int nt = 0; nt < 8; ++nt) {
            bf16x8 bfr = *(const bf16x8*)(brow + nt * 4096 + kc);
            acc[nt] = __builtin_amdgcn_mfma_f32_16x16x32_bf16(af, bfr, acc[nt], 0, 0, 0);
        }
    }
    #pragma unroll
    for (int nt = 0; nt < 8; ++nt) {
        const int col = nt * 16 + lm;
        const float bias = b3[col];
        #pragma unroll
        for (int r = 0; r < 4; ++r) {
            const int row = m0 + quad * 4 + r;
            C[(size_t)row * 128 + col] = fmaxf(acc[nt][r] + bias, 0.f);
        }
    }
}

// logits + softmax per batch row; 1024 thr, wave butterfly reduction
__global__ __launch_bounds__(1024) void k3_head(
    const float* __restrict__ feat,   // [256][16384]
    const float* __restrict__ wl,     // [3][16384]
    const float* __restrict__ bl,     // [3]
    float* __restrict__ out)          // [256][3]
{
    __shared__ float red[3][16];
    const int b = blockIdx.x, tid = threadIdx.x;
    const float4* f4 = (const float4*)(feat + (size_t)b * 16384);
    const float4* u0 = (const float4*)(wl);
    const float4* u1 = (const float4*)(wl + 16384);
    const float4* u2 = (const float4*)(wl + 32768);
    float a0 = 0.f, a1 = 0.f, a2 = 0.f;
    #pragma unroll
    for (int it = 0; it < 4; ++it) {
        int k = tid + it * 1024;
        float4 v  = f4[k];
        float4 w0 = u0[k], w1 = u1[k], w2 = u2[k];
        a0 = fmaf(v.x, w0.x, fmaf(v.y, w0.y, fmaf(v.z, w0.z, fmaf(v.w, w0.w, a0))));
        a1 = fmaf(v.x, w1.x, fmaf(v.y, w1.y, fmaf(v.z, w1.z, fmaf(v.w, w1.w, a1))));
        a2 = fmaf(v.x, w2.x, fmaf(v.y, w2.y, fmaf(v.z, w2.z, fmaf(v.w, w2.w, a2))));
    }
    #pragma unroll
    for (int off = 32; off > 0; off >>= 1) {
        a0 += __shfl_xor(a0, off);
        a1 += __shfl_xor(a1, off);
        a2 += __shfl_xor(a2, off);
    }
    if ((tid & 63) == 0) {
        int wv = tid >> 6;
        red[0][wv] = a0; red[1][wv] = a1; red[2][wv] = a2;
    }
    __syncthreads();
    if (tid == 0) {
        float l0 = bl[0], l1 = bl[1], l2 = bl[2];
        #pragma unroll
        for (int i = 0; i < 16; ++i) {
            l0 += red[0][i]; l1 += red[1][i]; l2 += red[2][i];
        }
        float m  = fmaxf(l0, fmaxf(l1, l2));
        float e0 = expf(l0 - m), e1 = expf(l1 - m), e2 = expf(l2 - m);
        float sm = e0 + e1 + e2;
        out[b * 3 + 0] = e0 / sm;
        out[b * 3 + 1] = e1 / sm;
        out[b * 3 + 2] = e2 / sm;
    }
}

extern "C" void kernel_launch(void* const* d_in, const int* in_sizes, int n_in,
                              void* d_out, int out_size, void* d_ws, size_t ws_size,
                              hipStream_t stream) {
    const float* x  = (const float*)d_in[0];
    const float* w1 = (const float*)d_in[1];
    const float* b1 = (const float*)d_in[2];
    const float* w2 = (const float*)d_in[3];
    const float* b2 = (const float*)d_in[4];
    const float* w3 = (const float*)d_in[5];
    const float* b3 = (const float*)d_in[6];
    const float* wl = (const float*)d_in[7];
    const float* bl = (const float*)d_in[8];
    float* out = (float*)d_out;

    // ws layout (~79.8 MB; fill counters show d_ws >= 600 MB):
    //   [0, 62914560)             h1g [10][32768][96] bf16
    //   [0, 16777216)             feat [32768][128] f32 (aliases dead h1g)
    //   [62914560, 79691776)      h2p [32768][256] bf16
    //   [79691776, 79704064)      w2b
    //   [79704064, 79769600)      w3b
    ushort* h1g  = (ushort*)d_ws;
    float*  feat = (float*)d_ws;
    ushort* h2p  = (ushort*)((char*)d_ws + 62914560);
    ushort* w2b  = (ushort*)((char*)d_ws + 79691776);
    ushort* w3b  = (ushort*)((char*)d_ws + 79704064);

    k0_prep<<<152, 256, 0, stream>>>(w2, w2b, w3, w3b);
    k1a_conv1<<<BN * 30 / 256, 256, 0, stream>>>(x, w1, b1, h1g);
    k1b_conv2<<<BN / 16, 256, 0, stream>>>(h1g, w2b, b2, h2p);
    k2_gemm<<<512, 256, 0, stream>>>(h2p, w3b, b3, feat);
    k3_head<<<256, 1024, 0, stream>>>(feat, wl, bl, out);
}

// Round 6
// 326.893 us; speedup vs baseline: 3.4858x; 1.0044x over previous
//
#include <hip/hip_runtime.h>
#include <math.h>

// Fully-fused pipeline, one heavyweight kernel + prep + softmax:
//   k0    : w2 [64][32][3] -> w2b bf16 [64][96] (k=s*32+ci); w3 -> w3b bf16
//   k_fused: wave = 16 series end-to-end, barrier-free:
//     conv1+pool1 computed per-lane in EXACT MFMA-A layout (lane(quad,lm) ->
//     series lm, channels quad*8..+7)  ->  conv2 = 16x16x32 MFMA vs w2b
//     -> bias+relu+pool2+relu per-lane (D: row=quad*4+reg, col=lm)
//     -> packed bf16 via wave-private LDS tile (the only transpose)
//     -> conv3 GEMM (K=256) vs w3b -> relu -> logits partials vs wl
//     -> wave butterfly -> per-block partial[512][3]
//   k_soft: 1 block: logits = sum partials + bl, softmax -> out [256][3]
// No h1/h2/feat intermediates in HBM: only x (190 MB) is read.

typedef __attribute__((ext_vector_type(8))) short bf16x8;
typedef __attribute__((ext_vector_type(4))) float f32x4;

__device__ __forceinline__ ushort f2bf(float f) {
    union { float f; uint u; } c; c.f = f;
    return (ushort)((c.u + 0x7FFFu + ((c.u >> 16) & 1u)) >> 16);   // RNE
}

#define S2 264   // sh2 row stride (ushorts): 528B rows, 16B-aligned

__global__ void k0_prep(const float* __restrict__ w2, ushort* __restrict__ w2b,
                        const float* __restrict__ w3, ushort* __restrict__ w3b) {
    int i = blockIdx.x * 256 + threadIdx.x;
    if (i < 6144) {                     // w2[c][ci][d] -> w2b[c][d*32+ci]
        int c = i / 96, r = i - c * 96;
        int ci = r / 3, d = r - ci * 3;
        w2b[c * 96 + d * 32 + ci] = f2bf(w2[i]);
    }
    int j = i - 6144;
    if (j >= 0 && j < 32768) w3b[j] = f2bf(w3[j]);
}

__global__ __launch_bounds__(256) void k_fused(
    const float* __restrict__ x,     // [32768][1216]
    const float* __restrict__ w1,    // [32][10]
    const float* __restrict__ b1,    // [32]
    const ushort* __restrict__ w2b,  // [64][96]
    const float* __restrict__ b2,    // [64]
    const ushort* __restrict__ w3b,  // [128][256]
    const float* __restrict__ b3,    // [128]
    const float* __restrict__ wl,    // [3][16384]
    float* __restrict__ partials)    // [512][3]
{
    __shared__ ushort sh2[4 * 16 * S2];     // wave-private 16x256 bf16 tiles
    __shared__ float red[4][3];
    const int wave = threadIdx.x >> 6, lane = threadIdx.x & 63;
    const int lm   = lane & 15, quad = lane >> 4;
    const int bn0  = blockIdx.x * 64 + wave * 16;
    const float* xr = x + (size_t)(bn0 + lm) * 1216;

    // hoist this lane's conv1 weights: channels quad*8..quad*8+7
    float wv[8][10], b1v[8];
    #pragma unroll
    for (int h = 0; h < 8; ++h) {
        const float* wr = w1 + (quad * 8 + h) * 10;     // 4 distinct addrs/wave
        #pragma unroll
        for (int kk = 0; kk < 5; ++kk) {
            float2 t = *(const float2*)(wr + 2 * kk);
            wv[h][2*kk] = t.x; wv[h][2*kk+1] = t.y;
        }
        b1v[h] = b1[quad * 8 + h];
    }
    float bias2[4];
    #pragma unroll
    for (int nt = 0; nt < 4; ++nt) bias2[nt] = b2[nt * 16 + lm];

    // ---- conv1 -> conv2 MFMA -> pool2, q = conv2 output position
    f32x4 cur[4];
    #pragma unroll
    for (int nt = 0; nt < 4; ++nt) cur[nt] = (f32x4){-3e38f,-3e38f,-3e38f,-3e38f};
    uint2 pk[4][4];                         // packed pooled bf16 [nt][r]

    for (int q = 0; q < 10; ++q) {          // dynamic: keep icache small
        f32x4 acc[4];
        #pragma unroll
        for (int nt = 0; nt < 4; ++nt) acc[nt] = (f32x4){0.f,0.f,0.f,0.f};

        #pragma unroll
        for (int kc = 0; kc < 3; ++kc) {
            const int p = 3 * q + kc;       // conv1-pooled position 0..29
            const int base = 40 * p - 4;    // 16B-aligned window
            float xw[48];
            {
                const float4* xp4 = (const float4*)(xr + base);
                #pragma unroll
                for (int i = 0; i < 12; ++i) {
                    float4 v;
                    if (i == 0) {
                        if (base >= 0) v = xp4[0];                  // uniform
                        else v = make_float4(0.f, 0.f, 0.f, 0.f);   // p==0 pad
                    } else v = xp4[i];
                    xw[4*i] = v.x; xw[4*i+1] = v.y; xw[4*i+2] = v.z; xw[4*i+3] = v.w;
                }
            }
            union { ushort u[8]; bf16x8 v; } af;
            #pragma unroll
            for (int h = 0; h < 8; ++h) {   // conv1 K=10 s=8 p=1 + relu + pool5
                float mx = 0.f;
                #pragma unroll
                for (int dt = 0; dt < 5; ++dt) {
                    float a = b1v[h];
                    #pragma unroll
                    for (int k = 0; k < 10; ++k)
                        a = fmaf(wv[h][k], xw[8*dt + 3 + k], a);
                    mx = fmaxf(mx, a);
                }
                af.u[h] = f2bf(mx);
            }
            #pragma unroll
            for (int nt = 0; nt < 4; ++nt) {   // w2b frags from L1 (12KB hot)
                bf16x8 bfr = *(const bf16x8*)(w2b + (nt*16+lm)*96 + kc*32 + quad*8);
                acc[nt] = __builtin_amdgcn_mfma_f32_16x16x32_bf16(af.v, bfr, acc[nt], 0, 0, 0);
            }
        }

        // pool2 windows over q: {0,1},{2,3,4},{5,6,7},{8,9}  (wave-uniform)
        const bool fresh = (q == 0 || q == 2 || q == 5 || q == 8);
        #pragma unroll
        for (int nt = 0; nt < 4; ++nt)
            #pragma unroll
            for (int r = 0; r < 4; ++r)
                cur[nt][r] = fresh ? acc[nt][r] : fmaxf(cur[nt][r], acc[nt][r]);

        if (q == 1 || q == 4 || q == 7 || q == 9) {     // window end
            const int w = (q == 1) ? 0 : (q == 4) ? 1 : (q == 7) ? 2 : 3;
            #pragma unroll
            for (int nt = 0; nt < 4; ++nt)
                #pragma unroll
                for (int r = 0; r < 4; ++r) {
                    float f = fmaxf(cur[nt][r] + bias2[nt], 0.f);
                    uint hb = (uint)f2bf(f);
                    if (w == 0)      pk[nt][r].x  = hb;
                    else if (w == 1) pk[nt][r].x |= hb << 16;
                    else if (w == 2) pk[nt][r].y  = hb;
                    else             pk[nt][r].y |= hb << 16;
                }
        }
    }

    // ---- transpose via wave-private LDS: rows = series, k = c2*4 + lp
    ushort* shw = sh2 + wave * 16 * S2;
    #pragma unroll
    for (int nt = 0; nt < 4; ++nt)
        #pragma unroll
        for (int r = 0; r < 4; ++r)
            *(uint2*)(shw + (quad*4 + r) * S2 + (nt*16 + lm) * 4) = pk[nt][r];

    // ---- conv3 GEMM (16 series x 128 cols, K=256) + logits partials
    bf16x8 afr[8];
    #pragma unroll
    for (int kc = 0; kc < 8; ++kc)          // A-frag: row lm, 16B contiguous
        afr[kc] = *(const bf16x8*)(shw + lm * S2 + kc * 32 + quad * 8);

    const int node0 = bn0 & 127;
    const float* wlr = wl + (node0 + quad * 4) * 128 + lm;
    float a0 = 0.f, a1 = 0.f, a2 = 0.f;
    for (int nt3 = 0; nt3 < 8; ++nt3) {     // dynamic: small icache
        f32x4 acc3 = (f32x4){0.f, 0.f, 0.f, 0.f};
        const ushort* bb = w3b + (size_t)(nt3 * 16 + lm) * 256 + quad * 8;
        #pragma unroll
        for (int kc = 0; kc < 8; ++kc) {
            bf16x8 bf3 = *(const bf16x8*)(bb + kc * 32);
            acc3 = __builtin_amdgcn_mfma_f32_16x16x32_bf16(afr[kc], bf3, acc3, 0, 0, 0);
        }
        const float b3v = b3[nt3 * 16 + lm];
        #pragma unroll
        for (int r = 0; r < 4; ++r) {       // feat value, never materialized
            float f = fmaxf(acc3[r] + b3v, 0.f);
            const float* wp = wlr + r * 128 + nt3 * 16;
            a0 = fmaf(f, wp[0],     a0);
            a1 = fmaf(f, wp[16384], a1);
            a2 = fmaf(f, wp[32768], a2);
        }
    }

    #pragma unroll
    for (int off = 32; off > 0; off >>= 1) {
        a0 += __shfl_xor(a0, off);
        a1 += __shfl_xor(a1, off);
        a2 += __shfl_xor(a2, off);
    }
    if (lane == 0) { red[wave][0] = a0; red[wave][1] = a1; red[wave][2] = a2; }
    __syncthreads();
    if (threadIdx.x < 3) {
        float s = red[0][threadIdx.x] + red[1][threadIdx.x]
                + red[2][threadIdx.x] + red[3][threadIdx.x];
        partials[blockIdx.x * 3 + threadIdx.x] = s;
    }
}

// logits = partials[2b] + partials[2b+1] + bl -> softmax
__global__ void k_soft(const float* __restrict__ partials,
                       const float* __restrict__ bl,
                       float* __restrict__ out) {
    const int b = threadIdx.x;      // 256 batches, 1 block
    float l0 = partials[(2*b)*3+0] + partials[(2*b+1)*3+0] + bl[0];
    float l1 = partials[(2*b)*3+1] + partials[(2*b+1)*3+1] + bl[1];
    float l2 = partials[(2*b)*3+2] + partials[(2*b+1)*3+2] + bl[2];
    float m  = fmaxf(l0, fmaxf(l1, l2));
    float e0 = expf(l0 - m), e1 = expf(l1 - m), e2 = expf(l2 - m);
    float s  = e0 + e1 + e2;
    out[b*3+0] = e0 / s; out[b*3+1] = e1 / s; out[b*3+2] = e2 / s;
}

extern "C" void kernel_launch(void* const* d_in, const int* in_sizes, int n_in,
                              void* d_out, int out_size, void* d_ws, size_t ws_size,
                              hipStream_t stream) {
    const float* x  = (const float*)d_in[0];
    const float* w1 = (const float*)d_in[1];
    const float* b1 = (const float*)d_in[2];
    const float* w2 = (const float*)d_in[3];
    const float* b2 = (const float*)d_in[4];
    const float* w3 = (const float*)d_in[5];
    const float* b3 = (const float*)d_in[6];
    const float* wl = (const float*)d_in[7];
    const float* bl = (const float*)d_in[8];
    float* out = (float*)d_out;

    // tiny ws: w2b 12KB | w3b 64KB | partials 6KB
    ushort* w2b      = (ushort*)d_ws;
    ushort* w3b      = (ushort*)((char*)d_ws + 16384);
    float*  partials = (float*)((char*)d_ws + 16384 + 65536);

    k0_prep<<<152, 256, 0, stream>>>(w2, w2b, w3, w3b);
    k_fused<<<512, 256, 0, stream>>>(x, w1, b1, w2b, b2, w3b, b3, wl, partials);
    k_soft<<<1, 256, 0, stream>>>(partials, bl, out);
}